// Round 2
// baseline (3490.120 us; speedup 1.0000x reference)
//
#include <hip/hip_runtime.h>

#define B_    512
#define L_    16
#define IN_   128
#define H_    1024
#define T_    64
#define OUTROW 10240   /* (L_+T_)*IN_ */

#define LDC   1040     /* c state fp32 row stride (padded) */
#define LDXL  144      /* XL fp32 row stride */
#define RST   68       /* padded f32 row stride in LDS red buffer (68*4 = 16B-aligned) */

/* ---- fragment-linear bf16 operand layout ----
   fragment = 16 rows x 32 k-cols = 1024B, lane-linear:
     elem(row,k) @ u16 index  frag*512 + ((k&31)>>3)*128 + (row&15)*8 + (k&7)
     frag = (row>>4)*KH + (k>>5),  KH = K/32 */
#define KH_X  64   /* Xb   : 2048 cols */
#define KH_H  32   /* H    : 1024 cols */
#define KH_XL 4    /* XLbf : 128 cols  */
#define KH_W0 36   /* W0c  : 1152      */
#define KH_W1 64   /* W1c  : 2048      */
#define KH_WO 32   /* Woutb: 1024      */

typedef __attribute__((ext_vector_type(8))) short bf8;
typedef __attribute__((ext_vector_type(4))) float f4;
typedef __attribute__((ext_vector_type(4))) unsigned short us4;
typedef unsigned short u16;
typedef unsigned int   u32;

#define MFMA16(a, b, c) __builtin_amdgcn_mfma_f32_16x16x32_bf16(a, b, c, 0, 0, 0)

__device__ __forceinline__ u16 f2bf(float f) {
    u32 u = __builtin_bit_cast(u32, f);
    u32 r = (u + 0x7fffu + ((u >> 16) & 1u)) >> 16;
    return (u16)r;
}
__device__ __forceinline__ float sigm(float x) { return 1.f / (1.f + __expf(-x)); }
__device__ __forceinline__ float tanh_f(float x) {
    float ax = fabsf(x);
    float e = __expf(-2.f * ax);
    float t = (1.f - e) / (1.f + e);
    return x < 0.f ? -t : t;
}
__device__ __forceinline__ bf8 ld8(const u16* p) { return *(const bf8*)p; }

__device__ __forceinline__ size_t swz(int kh_stride, int row, int k) {
    return ((size_t)(row >> 4) * kh_stride + (k >> 5)) * 512
           + ((k & 31) >> 3) * 128 + (row & 15) * 8 + (k & 7);
}

// ---- shared GEMM loop: 8-wave in-block split-K, single-buffered (TLP-reliant).
// Wave ws owns K-tiles kt === ws (mod 8); full 64x64 output fragments.
// All K strides are compile-time constants (3 instantiations) to keep VGPR<=128.
template<int KH0, int NK1, int KH1, int NK2, int KHB>
__device__ __forceinline__ void gemm_loop(f4 (&acc)[4][4], int tm, int tn,
    int lane, int ws,
    const u16* __restrict__ pA0, const u16* __restrict__ pA1,
    const u16* __restrict__ pB)
{
#pragma unroll
    for (int i = 0; i < 4; ++i)
#pragma unroll
        for (int j = 0; j < 4; ++j) acc[i][j] = (f4)(0.f);

    const int lo = lane * 8;
    const int nk  = NK1 + NK2;
    const int myn = (nk - ws + 7) >> 3;

    bf8 A[4], B[4];
    for (int m = 0; m < myn; ++m) {
        const int kt = ws + m * 8;
        const bool ix = kt < NK1;
        const int khA = (ix ? kt : kt - NK1) * 2;
        const int khB = kt * 2;
        const u16* ap = ix ? pA0 : pA1;
        const int khs = ix ? KH0 : KH1;
#pragma unroll
        for (int s = 0; s < 2; ++s) {
#pragma unroll
            for (int g = 0; g < 4; ++g)
                A[g] = ld8(ap + ((size_t)(tm * 4 + g) * khs + khA + s) * 512 + lo);
#pragma unroll
            for (int t = 0; t < 4; ++t)
                B[t] = ld8(pB + ((size_t)(tn * 4 + t) * KHB + khB + s) * 512 + lo);
#pragma unroll
            for (int g = 0; g < 4; ++g)
#pragma unroll
                for (int t = 0; t < 4; ++t)
                    acc[g][t] = MFMA16(A[g], B[t], acc[g][t]);
        }
    }
}

// ---- LSTM cell body: gemm_loop + 2-round chunked 8-copy LDS reduction +
// fused cell epilogue (c RMW value + bias prefetched at entry).
template<int KH0, int NK1, int KH1, int NK2, int KHB>
__device__ __forceinline__ void cell_body(int bid,
    const u16* __restrict__ pA0, const u16* __restrict__ pA1,
    const u16* __restrict__ pB, const float* __restrict__ bias,
    float* __restrict__ Cst, u16* __restrict__ Hdst, float* red)
{
    const int tn = (bid & 7) * 8 + ((bid >> 3) & 7);   // XCD-pins tn slice
    const int tm = bid >> 6;
    const int tid = threadIdx.x;                        // 0..511
    const int lane = tid & 63, ws = tid >> 6;
    const int l15 = lane & 15, qd = lane >> 4;

    // epilogue coords; prefetch c RMW values + bias now (hidden under GEMM)
    const int eu = tid & 15, elr = tid >> 4;            // unit 0..15, row 0..31
    const int ecol = tn * 16 + eu;
    const float cold0 = Cst[(size_t)(tm * 64 + elr) * LDC + ecol];
    const float cold1 = Cst[(size_t)(tm * 64 + 32 + elr) * LDC + ecol];
    f4 bi;
#pragma unroll
    for (int G = 0; G < 4; ++G) bi[G] = bias[tn * 64 + G * 16 + eu];

    f4 acc[4][4];
    gemm_loop<KH0, NK1, KH1, NK2, KHB>(acc, tm, tn, lane, ws, pA0, pA1, pB);

    // 2-round chunked reduction: round r covers rows r*32 .. r*32+31
#pragma unroll
    for (int round = 0; round < 2; ++round) {
        if (round) __syncthreads();     // round-0 reads done before re-dump
#pragma unroll
        for (int rh = 0; rh < 2; ++rh) {
            const int rg = round * 2 + rh;
#pragma unroll
            for (int t = 0; t < 4; ++t)
#pragma unroll
                for (int r = 0; r < 4; ++r)
                    red[ws * (32 * RST) + (rh * 16 + qd * 4 + r) * RST + t * 16 + l15]
                        = acc[rg][t][r];
        }
        __syncthreads();

        float g4[4];
#pragma unroll
        for (int G = 0; G < 4; ++G) {
            float s = 0.f;
#pragma unroll
            for (int w = 0; w < 8; ++w)
                s += red[w * (32 * RST) + elr * RST + G * 16 + eu];
            g4[G] = s + bi[G];
        }
        const float I  = sigm(g4[0]);
        const float F  = sigm(g4[1]);
        const float Gg = tanh_f(g4[2]);
        const float O  = sigm(g4[3]);
        const int grow = tm * 64 + round * 32 + elr;
        const float cn = F * (round ? cold1 : cold0) + I * Gg;
        Cst[(size_t)grow * LDC + ecol] = cn;
        Hdst[swz(KH_H, grow, ecol)] = f2bf(O * tanh_f(cn));
    }
}

__global__ __launch_bounds__(512, 4) void cell_prompt0(
    const u16* __restrict__ pA0, const u16* __restrict__ pA1,
    const u16* __restrict__ pB, const float* __restrict__ bias,
    float* __restrict__ Cst, u16* __restrict__ Hdst)
{
    __shared__ float red[8 * 32 * RST];
    cell_body<KH_X, 2, KH_H, 16, KH_W0>(blockIdx.x, pA0, pA1, pB, bias, Cst, Hdst, red);
}

__global__ __launch_bounds__(512, 4) void cell_roll0(
    const u16* __restrict__ pA0, const u16* __restrict__ pA1,
    const u16* __restrict__ pB, const float* __restrict__ bias,
    float* __restrict__ Cst, u16* __restrict__ Hdst)
{
    __shared__ float red[8 * 32 * RST];
    cell_body<KH_XL, 2, KH_H, 16, KH_W0>(blockIdx.x, pA0, pA1, pB, bias, Cst, Hdst, red);
}

__global__ __launch_bounds__(512, 4) void cell_l1(
    const u16* __restrict__ pA0, const u16* __restrict__ pA1,
    const u16* __restrict__ pB, const float* __restrict__ bias,
    float* __restrict__ Cst, u16* __restrict__ Hdst)
{
    __shared__ float red[8 * 32 * RST];
    cell_body<KH_H, 16, KH_H, 16, KH_W1>(blockIdx.x, pA0, pA1, pB, bias, Cst, Hdst, red);
}

// ---- prompt pairing: blocks 0..511 run cell1(t); 512..1023 run cell0(t+1).
// Both only read prior-dispatch data (H0(t), H1(t-1), Xb) and write disjoint
// buffers (H1/c1 vs H0/c0) -> valid in one dispatch, saves a launch gap.
__global__ __launch_bounds__(512, 4) void pair_k(
    const u16* __restrict__ A0a, const u16* __restrict__ A1a,
    const u16* __restrict__ Ba, const float* __restrict__ ba,
    float* __restrict__ Ca, u16* __restrict__ Ha,
    const u16* __restrict__ A0b, const u16* __restrict__ A1b,
    const u16* __restrict__ Bb, const float* __restrict__ bb,
    float* __restrict__ Cb, u16* __restrict__ Hb)
{
    __shared__ float red[8 * 32 * RST];
    if (blockIdx.x < 512)
        cell_body<KH_H, 16, KH_H, 16, KH_W1>(blockIdx.x, A0a, A1a, Ba, ba, Ca, Ha, red);
    else
        cell_body<KH_X, 2, KH_H, 16, KH_W0>(blockIdx.x - 512, A0b, A1b, Bb, bb, Cb, Hb, red);
}

// ---- Output projection: same 8-wave split-K loop + fused epilogue.
// Grid 16 (tn 0..1 x tm 0..7). xl = xin + h1 @ Wout^T + b_out.
__global__ __launch_bounds__(512, 4) void proj_gemm(
    const u16* __restrict__ pA, const u16* __restrict__ pB,
    const float* __restrict__ bout,
    const float* __restrict__ xin, int ldxin,
    float* __restrict__ XL, u16* __restrict__ XLbf,
    float* __restrict__ dout, int slot)
{
    __shared__ float red[8 * 32 * RST];
    const int bid = blockIdx.x;
    const int tn = bid >> 3, tm = bid & 7;
    const int tid = threadIdx.x;
    const int lane = tid & 63, ws = tid >> 6;
    const int l15 = lane & 15, qd = lane >> 4;

    // epilogue coords + prefetch (f4 quad per thread per round)
    const int elr = tid >> 4;            // 0..31
    const int c4  = (tid & 15) * 4;      // 0..60
    const int col = tn * 64 + c4;
    const f4 bo  = *(const f4*)&bout[col];
    const f4 xv0 = *(const f4*)&xin[(size_t)(tm * 64 + elr) * ldxin + col];
    const f4 xv1 = *(const f4*)&xin[(size_t)(tm * 64 + 32 + elr) * ldxin + col];

    f4 acc[4][4];
    gemm_loop<KH_H, 16, KH_H, 0, KH_WO>(acc, tm, tn, lane, ws, pA, pA, pB);

#pragma unroll
    for (int round = 0; round < 2; ++round) {
        if (round) __syncthreads();
#pragma unroll
        for (int rh = 0; rh < 2; ++rh) {
            const int rg = round * 2 + rh;
#pragma unroll
            for (int t = 0; t < 4; ++t)
#pragma unroll
                for (int r = 0; r < 4; ++r)
                    red[ws * (32 * RST) + (rh * 16 + qd * 4 + r) * RST + t * 16 + l15]
                        = acc[rg][t][r];
        }
        __syncthreads();

        f4 s = (f4)(0.f);
#pragma unroll
        for (int w = 0; w < 8; ++w)
            s += *(const f4*)&red[w * (32 * RST) + elr * RST + c4];
        const f4 v = (round ? xv1 : xv0) + s + bo;
        const int grow = tm * 64 + round * 32 + elr;
        *(f4*)&XL[(size_t)grow * LDXL + col] = v;
        us4 b;
#pragma unroll
        for (int j = 0; j < 4; ++j) b[j] = f2bf(v[j]);
        *(us4*)&XLbf[swz(KH_XL, grow, col)] = b;
        *(f4*)&dout[(size_t)grow * OUTROW + slot * IN_ + col] = v;
    }
}

// ---- Weight conversion: fp32 -> bf16 fragment-linear, gate-permuted rows,
// fused biases. One block per fragment; thread t writes u32 pair (coalesced).
__global__ void conv_w(const float* Wih0, const float* Whh0, const float* bih0, const float* bhh0,
                       const float* Wih1, const float* Whh1, const float* bih1, const float* bhh1,
                       const float* Wout,
                       u16* W0c, float* b0p, u16* W1c, float* b1p, u16* Woutb)
{
    const int bid = blockIdx.x, t = threadIdx.x;
    const int lane = t >> 2;              // fragment lane 0..63
    const int l15 = lane & 15, qd = lane >> 4;
    const int j0 = (t & 3) * 2;
    const int c0_ = qd * 8 + j0;

    if (bid < 9216) {                     // W0c: 256 rowgrps x 36 kh
        const int rg = bid / 36, kh = bid - rg * 36;
        const int p = rg * 16 + l15;
        const int rem = p & 63, G = rem >> 4, u = (p >> 6) * 16 + (rem & 15);
        const int src = G * H_ + u;
        float e0, e1;
        if (kh < 4) {
            e0 = Wih0[(size_t)src * IN_ + kh * 32 + c0_];
            e1 = Wih0[(size_t)src * IN_ + kh * 32 + c0_ + 1];
        } else {
            e0 = Whh0[(size_t)src * H_ + (kh - 4) * 32 + c0_];
            e1 = Whh0[(size_t)src * H_ + (kh - 4) * 32 + c0_ + 1];
        }
        ((u32*)W0c)[(size_t)bid * 256 + t] = (u32)f2bf(e0) | ((u32)f2bf(e1) << 16);
        if (kh == 0 && qd == 0 && j0 == 0) b0p[p] = bih0[src] + bhh0[src];
    } else if (bid < 25600) {             // W1c: 256 rowgrps x 64 kh
        const int x = bid - 9216;
        const int rg = x >> 6, kh = x & 63;
        const int p = rg * 16 + l15;
        const int rem = p & 63, G = rem >> 4, u = (p >> 6) * 16 + (rem & 15);
        const int src = G * H_ + u;
        float e0, e1;
        if (kh < 32) {
            e0 = Wih1[(size_t)src * H_ + kh * 32 + c0_];
            e1 = Wih1[(size_t)src * H_ + kh * 32 + c0_ + 1];
        } else {
            e0 = Whh1[(size_t)src * H_ + (kh - 32) * 32 + c0_];
            e1 = Whh1[(size_t)src * H_ + (kh - 32) * 32 + c0_ + 1];
        }
        ((u32*)W1c)[(size_t)x * 256 + t] = (u32)f2bf(e0) | ((u32)f2bf(e1) << 16);
        if (kh == 0 && qd == 0 && j0 == 0) b1p[p] = bih1[src] + bhh1[src];
    } else {                              // Woutb: 8 rowgrps x 32 kh
        const int x = bid - 25600;
        const int rg = x >> 5, kh = x & 31;
        const int r = rg * 16 + l15;
        const float e0 = Wout[(size_t)r * H_ + kh * 32 + c0_];
        const float e1 = Wout[(size_t)r * H_ + kh * 32 + c0_ + 1];
        ((u32*)Woutb)[(size_t)x * 256 + t] = (u32)f2bf(e0) | ((u32)f2bf(e1) << 16);
    }
}

// ---- Setup: zero states, x -> bf16 fragment-linear staging, x -> out[:,0:16] ----
__global__ void setup_k(const float* __restrict__ x, u16* __restrict__ Xb,
                        u16* H0, u16* H1, float* c0, float* c1,
                        float* __restrict__ dout)
{
    const int i = blockIdx.x * 256 + threadIdx.x;  // < 512*16*128
    const float v = x[i];
    const int r = i >> 11, col = i & 2047;
    Xb[swz(KH_X, r, col)] = f2bf(v);
    dout[(size_t)r * OUTROW + col] = v;
    if (i < B_ * H_) {
        H0[i] = 0; H1[i] = 0;
        const int rr = i >> 10, cc = i & 1023;
        c0[(size_t)rr * LDC + cc] = 0.f; c1[(size_t)rr * LDC + cc] = 0.f;
    }
}

extern "C" void kernel_launch(void* const* d_in, const int* in_sizes, int n_in,
                              void* d_out, int out_size, void* d_ws, size_t ws_size,
                              hipStream_t stream)
{
    const float* x    = (const float*)d_in[0];
    const float* Wih0 = (const float*)d_in[1];
    const float* Whh0 = (const float*)d_in[2];
    const float* bih0 = (const float*)d_in[3];
    const float* bhh0 = (const float*)d_in[4];
    const float* Wih1 = (const float*)d_in[5];
    const float* Whh1 = (const float*)d_in[6];
    const float* bih1 = (const float*)d_in[7];
    const float* bhh1 = (const float*)d_in[8];
    const float* Wout = (const float*)d_in[9];
    const float* bout = (const float*)d_in[10];
    float* dout = (float*)d_out;

    char* ws = (char*)d_ws;
    size_t off = 0;
    auto alloc = [&](size_t bytes) -> char* {
        char* p = ws + off; off += (bytes + 255) & ~(size_t)255; return p;
    };
    u16*  W0c   = (u16*)alloc((size_t)9216 * 1024);
    u16*  W1c   = (u16*)alloc((size_t)16384 * 1024);
    u16*  Woutb = (u16*)alloc((size_t)256 * 1024);
    float* b0p  = (float*)alloc(4096 * 4);
    float* b1p  = (float*)alloc(4096 * 4);
    u16*  Xb    = (u16*)alloc((size_t)2048 * 1024);
    u16*  H0b[2]; H0b[0] = (u16*)alloc((size_t)1024 * 1024); H0b[1] = (u16*)alloc((size_t)1024 * 1024);
    u16*  H1b[2]; H1b[0] = (u16*)alloc((size_t)1024 * 1024); H1b[1] = (u16*)alloc((size_t)1024 * 1024);
    float* c0   = (float*)alloc((size_t)B_ * LDC * 4);
    float* c1   = (float*)alloc((size_t)B_ * LDC * 4);
    float* XL   = (float*)alloc((size_t)B_ * LDXL * 4);
    u16*  XLbf  = (u16*)alloc((size_t)128 * 1024);

    conv_w<<<25856, 256, 0, stream>>>(Wih0, Whh0, bih0, bhh0,
                                      Wih1, Whh1, bih1, bhh1, Wout,
                                      W0c, b0p, W1c, b1p, Woutb);
    setup_k<<<4096, 256, 0, stream>>>(x, Xb, H0b[0], H1b[0], c0, c1, dout);

    // ---- prompt: cell0(0); 15 x [cell1(t) || cell0(t+1)]; cell1(15); proj(15)
    int p = 0;
    cell_prompt0<<<512, 512, 0, stream>>>(Xb, H0b[0], W0c, b0p, c0, H0b[1]);
    for (int g = 0; g < 15; ++g) {
        pair_k<<<1024, 512, 0, stream>>>(
            H0b[1 - p], H1b[p], W1c, b1p, c1, H1b[1 - p],            // cell1(g)
            Xb + (size_t)(g + 1) * 2048, H0b[1 - p], W0c, b0p, c0, H0b[p]); // cell0(g+1)
        p ^= 1;
    }
    // here p = 1: cell0(15) wrote H0b[0]; latest H1 = H1b[1]
    cell_l1<<<512, 512, 0, stream>>>(H0b[0], H1b[1], W1c, b1p, c1, H1b[0]);
    proj_gemm<<<16, 512, 0, stream>>>(H1b[0], Woutb, bout,
                                      x + 15 * IN_, L_ * IN_, XL, XLbf, dout, 16);

    // ---- rollout: 63 steps, latest state in H0b[0]/H1b[0]
    p = 0;
    for (int g = 16; g < 79; ++g) {
        cell_roll0<<<512, 512, 0, stream>>>(XLbf, H0b[p], W0c, b0p, c0, H0b[1 - p]);
        cell_l1<<<512, 512, 0, stream>>>(H0b[1 - p], H1b[p], W1c, b1p, c1, H1b[1 - p]);
        const int s = g - 15;            // 1..63 -> out slot 16+s
        proj_gemm<<<16, 512, 0, stream>>>(H1b[1 - p], Woutb, bout,
                                          XL, LDXL, XL, XLbf, dout, 16 + s);
        p ^= 1;
    }
}

// Round 3
// 2623.269 us; speedup vs baseline: 1.3304x; 1.3304x over previous
//
#include <hip/hip_runtime.h>

#define B_    512
#define L_    16
#define IN_   128
#define H_    1024
#define T_    64
#define OUTROW 10240   /* (L_+T_)*IN_ */

#define LDC   1040     /* c state fp32 row stride (padded) */
#define LDXL  144      /* XL fp32 row stride */
#define RSTRIDE 67     /* padded fp32 row stride in LDS reduction buffer */
#define RSZ   (64 * RSTRIDE)

/* ---- fragment-linear bf16 operand layout ----
   fragment = 16 rows x 32 k-cols = 1024B, lane-linear:
     elem(row,k) @ u16 index  frag*512 + ((k&31)>>3)*128 + (row&15)*8 + (k&7)
     frag = (row>>4)*KH + (k>>5),  KH = K/32 */
#define KH_X  64   /* Xb   : 2048 cols */
#define KH_H  32   /* H    : 1024 cols */
#define KH_XL 4    /* XLbf : 128 cols  */
#define KH_W0 36   /* W0c  : 1152      */
#define KH_W1 64   /* W1c  : 2048      */
#define KH_WO 32   /* Woutb: 1024      */

typedef __attribute__((ext_vector_type(8))) short bf8;
typedef __attribute__((ext_vector_type(4))) float f4;
typedef __attribute__((ext_vector_type(4))) unsigned short us4;
typedef unsigned short u16;
typedef unsigned int   u32;

#define MFMA16(a, b, c) __builtin_amdgcn_mfma_f32_16x16x32_bf16(a, b, c, 0, 0, 0)

__device__ __forceinline__ u16 f2bf(float f) {
    u32 u = __builtin_bit_cast(u32, f);
    u32 r = (u + 0x7fffu + ((u >> 16) & 1u)) >> 16;
    return (u16)r;
}
__device__ __forceinline__ float sigm(float x) { return 1.f / (1.f + __expf(-x)); }
__device__ __forceinline__ float tanh_f(float x) {
    float ax = fabsf(x);
    float e = __expf(-2.f * ax);
    float t = (1.f - e) / (1.f + e);
    return x < 0.f ? -t : t;
}
__device__ __forceinline__ bf8 ld8(const u16* p) { return *(const bf8*)p; }

__device__ __forceinline__ size_t swz(int kh_stride, int row, int k) {
    return ((size_t)(row >> 4) * kh_stride + (k >> 5)) * 512
           + ((k & 31) >> 3) * 128 + (row & 15) * 8 + (k & 7);
}

// 16-MFMA pack on one 32-col fragment set
#define MFMAP(AS, BS)                                                       \
  do {                                                                      \
    _Pragma("unroll")                                                       \
    for (int g_ = 0; g_ < 4; ++g_)                                          \
      _Pragma("unroll")                                                     \
      for (int t_ = 0; t_ < 4; ++t_)                                        \
        acc[g_][t_] = MFMA16(AS[g_], BS[t_], acc[g_][t_]);                  \
  } while (0)

// Load fragment set for 32-col phase PH of this wave's sequence.
// Phase -> (kt = ws + (PH>>1)*4, s = PH&1); khalf offset = (kt*2+s)*512 u16.
#define LOADP_CELL(AS, BS, PH)                                              \
  do {                                                                      \
    const int kt_ = ws + (((PH) >> 1) << 2);                                \
    const int s_  = (PH) & 1;                                               \
    const bool ix_ = kt_ < nk1;                                             \
    const int oA_ = (((ix_ ? kt_ : kt_ - nk1) << 1) + s_) * 512;            \
    const int oB_ = ((kt_ << 1) + s_) * 512;                                \
    _Pragma("unroll")                                                       \
    for (int g_ = 0; g_ < 4; ++g_)                                          \
      AS[g_] = ld8((ix_ ? apx[g_] : aph[g_]) + oA_);                        \
    _Pragma("unroll")                                                       \
    for (int t_ = 0; t_ < 4; ++t_) BS[t_] = ld8(bp[t_] + oB_);              \
  } while (0)

#define LOADP_PROJ(AS, BS, PH)                                              \
  do {                                                                      \
    const int kt_ = ws + (((PH) >> 1) << 2);                                \
    const int o_  = ((kt_ << 1) + ((PH) & 1)) * 512;                        \
    _Pragma("unroll")                                                       \
    for (int g_ = 0; g_ < 4; ++g_) AS[g_] = ld8(ap[g_] + o_);               \
    _Pragma("unroll")                                                       \
    for (int t_ = 0; t_ < 4; ++t_) BS[t_] = ld8(bp[t_] + o_);               \
  } while (0)

// ---- LSTM cell body: 4-wave split-K GEMM with 4-deep (3-phase-ahead)
// register pipeline + LDS reduction + fused cell epilogue.
// Requires nph >= 8 (true for all shapes used: nk in {18, 32}).
__device__ __forceinline__ void cell_body(int bid,
    const u16* __restrict__ pA0, int kh0, int nk1,
    const u16* __restrict__ pA1, int kh1, int nk2,
    const u16* __restrict__ pB, int khB,
    const float* __restrict__ bias, float* __restrict__ Cst,
    u16* __restrict__ Hdst, float* __restrict__ red)
{
    const int tn = (bid & 7) * 8 + ((bid >> 3) & 7);   // XCD-pins tn slice
    const int tm = bid >> 6;
    const int tid = threadIdx.x;
    const int lane = tid & 63, ws = tid >> 6;
    const int l15 = lane & 15, qd = lane >> 4, q4 = qd * 4;

    // epilogue coords; prefetch c RMW values now (hidden under whole GEMM)
    const int erow = ws * 16 + l15;
    const int grow = tm * 64 + erow;
    const int colb = tn * 16 + q4;
    const f4 cold = *(const f4*)&Cst[(size_t)grow * LDC + colb];

    f4 acc[4][4];
#pragma unroll
    for (int i = 0; i < 4; ++i)
#pragma unroll
        for (int j = 0; j < 4; ++j) acc[i][j] = (f4)(0.f);

    const u16* bp[4];
#pragma unroll
    for (int t = 0; t < 4; ++t)
        bp[t] = pB + (size_t)(tn * 4 + t) * khB * 512 + lane * 8;
    const u16* apx[4];
    const u16* aph[4];
#pragma unroll
    for (int g = 0; g < 4; ++g) {
        apx[g] = pA0 + (size_t)(tm * 4 + g) * kh0 * 512 + lane * 8;
        aph[g] = pA1 + (size_t)(tm * 4 + g) * kh1 * 512 + lane * 8;
    }

    const int nk  = nk1 + nk2;
    const int myn = (nk - ws + 3) >> 2;     // K-tiles for this wave
    const int nph = myn * 2;                // 32-col phases (even, >= 8)

    bf8 A0[4], B0[4], A1[4], B1[4], A2[4], B2[4], A3[4], B3[4];
    LOADP_CELL(A0, B0, 0);
    LOADP_CELL(A1, B1, 1);
    LOADP_CELL(A2, B2, 2);
    int ph = 0;
    for (; ph + 4 <= nph; ph += 4) {
        LOADP_CELL(A3, B3, ph + 3);
        MFMAP(A0, B0);
        if (ph + 4 < nph) LOADP_CELL(A0, B0, ph + 4);
        MFMAP(A1, B1);
        if (ph + 5 < nph) LOADP_CELL(A1, B1, ph + 5);
        MFMAP(A2, B2);
        if (ph + 6 < nph) LOADP_CELL(A2, B2, ph + 6);
        MFMAP(A3, B3);
    }
    if (ph < nph) {                          // nph % 4 == 2 tail
        MFMAP(A0, B0);
        MFMAP(A1, B1);
    }

    // dump partials to padded LDS
#pragma unroll
    for (int rg = 0; rg < 4; ++rg)
#pragma unroll
        for (int t = 0; t < 4; ++t)
#pragma unroll
            for (int r = 0; r < 4; ++r)
                red[ws * RSZ + (rg * 16 + q4 + r) * RSTRIDE + t * 16 + l15] = acc[rg][t][r];
    __syncthreads();

    // distributed epilogue: wave ws -> rows ws*16+l15; units u15 = q4..q4+3
    f4 gs[4];
#pragma unroll
    for (int G = 0; G < 4; ++G) {
        f4 s;
#pragma unroll
        for (int j = 0; j < 4; ++j) {
            const int cidx = erow * RSTRIDE + G * 16 + q4 + j;
            s[j] = red[0 * RSZ + cidx] + red[1 * RSZ + cidx]
                 + red[2 * RSZ + cidx] + red[3 * RSZ + cidx];
        }
        gs[G] = s + *(const f4*)&bias[tn * 64 + G * 16 + q4];
    }
    f4 cn; us4 h4;
#pragma unroll
    for (int j = 0; j < 4; ++j) {
        const float I  = sigm(gs[0][j]);
        const float F  = sigm(gs[1][j]);
        const float Gg = tanh_f(gs[2][j]);
        const float O  = sigm(gs[3][j]);
        cn[j] = F * cold[j] + I * Gg;
        h4[j] = f2bf(O * tanh_f(cn[j]));
    }
    *(f4*)&Cst[(size_t)grow * LDC + colb] = cn;
    *(us4*)&Hdst[swz(KH_H, grow, colb)] = h4;
}

__global__ __launch_bounds__(256, 2) void cell_gemm(
    const u16* __restrict__ pA0, int kh0, int nk1,
    const u16* __restrict__ pA1, int kh1, int nk2,
    const u16* __restrict__ pB, int khB,
    const float* __restrict__ bias, float* __restrict__ Cst, u16* __restrict__ Hdst)
{
    __shared__ float red[4 * RSZ];
    cell_body(blockIdx.x, pA0, kh0, nk1, pA1, kh1, nk2, pB, khB, bias, Cst, Hdst, red);
}

// ---- prompt pairing: blocks 0..511 run cell1(t); 512..1023 run cell0(t+1).
// Both read only prior-dispatch data (H0(t), H1(t-1), Xb) and write disjoint
// buffers (H1/c1 vs H0/c0) -> valid in one dispatch, saves a launch gap.
__global__ __launch_bounds__(256, 2) void pair_k(
    const u16* __restrict__ A0a, int kh0a, int nk1a,
    const u16* __restrict__ A1a, int kh1a, int nk2a,
    const u16* __restrict__ Ba, int khBa,
    const float* __restrict__ ba, float* __restrict__ Ca, u16* __restrict__ Ha,
    const u16* __restrict__ A0b, int kh0b, int nk1b,
    const u16* __restrict__ A1b, int kh1b, int nk2b,
    const u16* __restrict__ Bb, int khBb,
    const float* __restrict__ bb, float* __restrict__ Cb, u16* __restrict__ Hb)
{
    __shared__ float red[4 * RSZ];
    if (blockIdx.x < 512)
        cell_body(blockIdx.x, A0a, kh0a, nk1a, A1a, kh1a, nk2a, Ba, khBa, ba, Ca, Ha, red);
    else
        cell_body(blockIdx.x - 512, A0b, kh0b, nk1b, A1b, kh1b, nk2b, Bb, khBb, bb, Cb, Hb, red);
}

// ---- Output projection: 4-wave split-K, same 4-deep pipeline (nph = 8).
// Grid 16 (tn 0..1 x tm 0..7). xl = xin + h1 @ Wout^T + b_out.
__global__ __launch_bounds__(256, 2) void proj_gemm(
    const u16* __restrict__ pA,   // H1 fragment-linear, KH_H
    const u16* __restrict__ pB,   // Woutb fragment-linear, KH_WO
    const float* __restrict__ bout,
    const float* __restrict__ xin, int ldxin,
    float* __restrict__ XL, u16* __restrict__ XLbf,
    float* __restrict__ dout, int slot)
{
    __shared__ float red[4 * RSZ];
    const int bid = blockIdx.x;
    const int tn = bid >> 3, tm = bid & 7;
    const int tid = threadIdx.x;
    const int lane = tid & 63, ws = tid >> 6;
    const int l15 = lane & 15, qd = lane >> 4;

    f4 acc[4][4];
#pragma unroll
    for (int i = 0; i < 4; ++i)
#pragma unroll
        for (int j = 0; j < 4; ++j) acc[i][j] = (f4)(0.f);

    const u16* bp[4];
#pragma unroll
    for (int t = 0; t < 4; ++t)
        bp[t] = pB + (size_t)(tn * 4 + t) * KH_WO * 512 + lane * 8;
    const u16* ap[4];
#pragma unroll
    for (int g = 0; g < 4; ++g)
        ap[g] = pA + (size_t)(tm * 4 + g) * KH_H * 512 + lane * 8;

    const int nph = 8;   // 16 K-tiles / 4 waves * 2 phases
    bf8 A0[4], B0[4], A1[4], B1[4], A2[4], B2[4], A3[4], B3[4];
    LOADP_PROJ(A0, B0, 0);
    LOADP_PROJ(A1, B1, 1);
    LOADP_PROJ(A2, B2, 2);
    for (int ph = 0; ph + 4 <= nph; ph += 4) {
        LOADP_PROJ(A3, B3, ph + 3);
        MFMAP(A0, B0);
        if (ph + 4 < nph) LOADP_PROJ(A0, B0, ph + 4);
        MFMAP(A1, B1);
        if (ph + 5 < nph) LOADP_PROJ(A1, B1, ph + 5);
        MFMAP(A2, B2);
        if (ph + 6 < nph) LOADP_PROJ(A2, B2, ph + 6);
        MFMAP(A3, B3);
    }

#pragma unroll
    for (int rg = 0; rg < 4; ++rg)
#pragma unroll
        for (int t = 0; t < 4; ++t)
#pragma unroll
            for (int r = 0; r < 4; ++r)
                red[ws * RSZ + (rg * 16 + qd * 4 + r) * RSTRIDE + t * 16 + l15] = acc[rg][t][r];
    __syncthreads();

    const int erow = ws * 16 + l15;
    const int grow = tm * 64 + erow;
#pragma unroll
    for (int jb = 0; jb < 4; ++jb) {
        const int cin = qd * 16 + jb * 4;
        const int col = tn * 64 + cin;
        f4 s;
#pragma unroll
        for (int j2 = 0; j2 < 4; ++j2) {
            const int cidx = erow * RSTRIDE + cin + j2;
            s[j2] = red[0 * RSZ + cidx] + red[1 * RSZ + cidx]
                  + red[2 * RSZ + cidx] + red[3 * RSZ + cidx];
        }
        const f4 v = *(const f4*)&xin[(size_t)grow * ldxin + col] + s
                     + *(const f4*)&bout[col];
        *(f4*)&XL[(size_t)grow * LDXL + col] = v;
        us4 b;
#pragma unroll
        for (int j2 = 0; j2 < 4; ++j2) b[j2] = f2bf(v[j2]);
        *(us4*)&XLbf[swz(KH_XL, grow, col)] = b;
        *(f4*)&dout[(size_t)grow * OUTROW + slot * IN_ + col] = v;
    }
}

// ---- Weight conversion: fp32 -> bf16 fragment-linear, gate-permuted rows,
// fused biases. One block per fragment; thread t writes u32 pair (coalesced).
__global__ void conv_w(const float* Wih0, const float* Whh0, const float* bih0, const float* bhh0,
                       const float* Wih1, const float* Whh1, const float* bih1, const float* bhh1,
                       const float* Wout,
                       u16* W0c, float* b0p, u16* W1c, float* b1p, u16* Woutb)
{
    const int bid = blockIdx.x, t = threadIdx.x;
    const int lane = t >> 2;              // fragment lane 0..63
    const int l15 = lane & 15, qd = lane >> 4;
    const int j0 = (t & 3) * 2;
    const int c0_ = qd * 8 + j0;

    if (bid < 9216) {                     // W0c: 256 rowgrps x 36 kh
        const int rg = bid / 36, kh = bid - rg * 36;
        const int p = rg * 16 + l15;
        const int rem = p & 63, G = rem >> 4, u = (p >> 6) * 16 + (rem & 15);
        const int src = G * H_ + u;
        float e0, e1;
        if (kh < 4) {
            e0 = Wih0[(size_t)src * IN_ + kh * 32 + c0_];
            e1 = Wih0[(size_t)src * IN_ + kh * 32 + c0_ + 1];
        } else {
            e0 = Whh0[(size_t)src * H_ + (kh - 4) * 32 + c0_];
            e1 = Whh0[(size_t)src * H_ + (kh - 4) * 32 + c0_ + 1];
        }
        ((u32*)W0c)[(size_t)bid * 256 + t] = (u32)f2bf(e0) | ((u32)f2bf(e1) << 16);
        if (kh == 0 && qd == 0 && j0 == 0) b0p[p] = bih0[src] + bhh0[src];
    } else if (bid < 25600) {             // W1c: 256 rowgrps x 64 kh
        const int x = bid - 9216;
        const int rg = x >> 6, kh = x & 63;
        const int p = rg * 16 + l15;
        const int rem = p & 63, G = rem >> 4, u = (p >> 6) * 16 + (rem & 15);
        const int src = G * H_ + u;
        float e0, e1;
        if (kh < 32) {
            e0 = Wih1[(size_t)src * H_ + kh * 32 + c0_];
            e1 = Wih1[(size_t)src * H_ + kh * 32 + c0_ + 1];
        } else {
            e0 = Whh1[(size_t)src * H_ + (kh - 32) * 32 + c0_];
            e1 = Whh1[(size_t)src * H_ + (kh - 32) * 32 + c0_ + 1];
        }
        ((u32*)W1c)[(size_t)x * 256 + t] = (u32)f2bf(e0) | ((u32)f2bf(e1) << 16);
        if (kh == 0 && qd == 0 && j0 == 0) b1p[p] = bih1[src] + bhh1[src];
    } else {                              // Woutb: 8 rowgrps x 32 kh
        const int x = bid - 25600;
        const int rg = x >> 5, kh = x & 31;
        const int r = rg * 16 + l15;
        const float e0 = Wout[(size_t)r * H_ + kh * 32 + c0_];
        const float e1 = Wout[(size_t)r * H_ + kh * 32 + c0_ + 1];
        ((u32*)Woutb)[(size_t)x * 256 + t] = (u32)f2bf(e0) | ((u32)f2bf(e1) << 16);
    }
}

// ---- Setup: zero states, x -> bf16 fragment-linear staging, x -> out[:,0:16] ----
__global__ void setup_k(const float* __restrict__ x, u16* __restrict__ Xb,
                        u16* H0, u16* H1, float* c0, float* c1,
                        float* __restrict__ dout)
{
    const int i = blockIdx.x * 256 + threadIdx.x;  // < 512*16*128
    const float v = x[i];
    const int r = i >> 11, col = i & 2047;
    Xb[swz(KH_X, r, col)] = f2bf(v);
    dout[(size_t)r * OUTROW + col] = v;
    if (i < B_ * H_) {
        H0[i] = 0; H1[i] = 0;
        const int rr = i >> 10, cc = i & 1023;
        c0[(size_t)rr * LDC + cc] = 0.f; c1[(size_t)rr * LDC + cc] = 0.f;
    }
}

extern "C" void kernel_launch(void* const* d_in, const int* in_sizes, int n_in,
                              void* d_out, int out_size, void* d_ws, size_t ws_size,
                              hipStream_t stream)
{
    const float* x    = (const float*)d_in[0];
    const float* Wih0 = (const float*)d_in[1];
    const float* Whh0 = (const float*)d_in[2];
    const float* bih0 = (const float*)d_in[3];
    const float* bhh0 = (const float*)d_in[4];
    const float* Wih1 = (const float*)d_in[5];
    const float* Whh1 = (const float*)d_in[6];
    const float* bih1 = (const float*)d_in[7];
    const float* bhh1 = (const float*)d_in[8];
    const float* Wout = (const float*)d_in[9];
    const float* bout = (const float*)d_in[10];
    float* dout = (float*)d_out;

    char* ws = (char*)d_ws;
    size_t off = 0;
    auto alloc = [&](size_t bytes) -> char* {
        char* p = ws + off; off += (bytes + 255) & ~(size_t)255; return p;
    };
    u16*  W0c   = (u16*)alloc((size_t)9216 * 1024);
    u16*  W1c   = (u16*)alloc((size_t)16384 * 1024);
    u16*  Woutb = (u16*)alloc((size_t)256 * 1024);
    float* b0p  = (float*)alloc(4096 * 4);
    float* b1p  = (float*)alloc(4096 * 4);
    u16*  Xb    = (u16*)alloc((size_t)2048 * 1024);
    u16*  H0b[2]; H0b[0] = (u16*)alloc((size_t)1024 * 1024); H0b[1] = (u16*)alloc((size_t)1024 * 1024);
    u16*  H1b[2]; H1b[0] = (u16*)alloc((size_t)1024 * 1024); H1b[1] = (u16*)alloc((size_t)1024 * 1024);
    float* c0   = (float*)alloc((size_t)B_ * LDC * 4);
    float* c1   = (float*)alloc((size_t)B_ * LDC * 4);
    float* XL   = (float*)alloc((size_t)B_ * LDXL * 4);
    u16*  XLbf  = (u16*)alloc((size_t)128 * 1024);

    conv_w<<<25856, 256, 0, stream>>>(Wih0, Whh0, bih0, bhh0,
                                      Wih1, Whh1, bih1, bhh1, Wout,
                                      W0c, b0p, W1c, b1p, Woutb);
    setup_k<<<4096, 256, 0, stream>>>(x, Xb, H0b[0], H1b[0], c0, c1, dout);

    // ---- prompt: cell0(0); 15 x [cell1(t) || cell0(t+1)]; cell1(15); proj(15)
    int p = 0;
    cell_gemm<<<512, 256, 0, stream>>>(Xb, KH_X, 2, H0b[0], KH_H, 16,
                                       W0c, KH_W0, b0p, c0, H0b[1]);
    for (int g = 0; g < 15; ++g) {
        pair_k<<<1024, 256, 0, stream>>>(
            H0b[1 - p], KH_H, 16, H1b[p], KH_H, 16, W1c, KH_W1, b1p, c1, H1b[1 - p],
            Xb + (size_t)(g + 1) * 2048, KH_X, 2, H0b[1 - p], KH_H, 16,
            W0c, KH_W0, b0p, c0, H0b[p]);
        p ^= 1;
    }
    // here p = 1: cell0(15) wrote H0b[0]; latest H1 = H1b[1]
    cell_gemm<<<512, 256, 0, stream>>>(H0b[0], KH_H, 16, H1b[1], KH_H, 16,
                                       W1c, KH_W1, b1p, c1, H1b[0]);
    proj_gemm<<<16, 256, 0, stream>>>(H1b[0], Woutb, bout,
                                      x + 15 * IN_, L_ * IN_, XL, XLbf, dout, 16);

    // ---- rollout: 63 steps, latest state H0 = H0b[0], H1 = H1b[0]
    p = 0;
    for (int g = 16; g < 79; ++g) {
        cell_gemm<<<512, 256, 0, stream>>>(XLbf, KH_XL, 2, H0b[p], KH_H, 16,
                                           W0c, KH_W0, b0p, c0, H0b[1 - p]);
        cell_gemm<<<512, 256, 0, stream>>>(H0b[1 - p], KH_H, 16, H1b[p], KH_H, 16,
                                           W1c, KH_W1, b1p, c1, H1b[1 - p]);
        const int s = g - 15;            // 1..63 -> out slot 16+s
        proj_gemm<<<16, 256, 0, stream>>>(H1b[1 - p], Woutb, bout,
                                          XL, LDXL, XL, XLbf, dout, 16 + s);
        p ^= 1;
    }
}